// Round 1
// baseline (533.586 us; speedup 1.0000x reference)
//
#include <hip/hip_runtime.h>

#define T_DIM 2048
#define B_DIM 8192

// DPP quad_perm helpers (cross-lane within quads, pure VALU)
__device__ __forceinline__ float qperm_xor1(float v) {  // lane gets value from lane^1
  int i = __float_as_int(v);
  return __int_as_float(__builtin_amdgcn_update_dpp(i, i, 0xB1, 0xF, 0xF, false)); // [1,0,3,2]
}
__device__ __forceinline__ float qperm_xor2(float v) {  // lane gets value from lane^2
  int i = __float_as_int(v);
  return __int_as_float(__builtin_amdgcn_update_dpp(i, i, 0x4E, 0xF, 0xF, false)); // [2,3,0,1]
}
// ds_swizzle xor4 (exchange across the two halves of the 8-lane group)
__device__ __forceinline__ float swz_xor4(float v) {
  return __int_as_float(__builtin_amdgcn_ds_swizzle(__float_as_int(v), 0x101F)); // xor_mask=4, and=0x1F
}

__global__ __launch_bounds__(256) void lstm_scan_kernel(
    const float* __restrict__ x,
    const float* __restrict__ w_ih, const float* __restrict__ w_hh,
    const float* __restrict__ b_ih, const float* __restrict__ b_hh,
    const float* __restrict__ w_lin, const float* __restrict__ b_lin,
    float* __restrict__ out)
{
  const int tid = blockIdx.x * blockDim.x + threadIdx.x;
  const int l = tid & 7;          // lane within 8-lane group (one group per batch elem)
  const int b = tid >> 3;         // batch element
  const int e = l & 3;            // hidden element this lane owns
  const bool half0 = (l & 4) == 0; // half0: rows {e (i), 8+e (g)}; half1: {4+e (f), 12+e (o)}

  // Gate rows owned by this lane (PyTorch order: i,f,g,o blocks of H=4)
  const int rA = (half0 ? 0 : 4) + e;   // i (half0) or f (half1)
  const int rB = 8 + (half0 ? 0 : 4) + e; // g (half0) or o (half1)

  // Pre-permuted weights: broadcast order is [e, e^1, e^2, e^3]
  float wihA[4], whhA[4], wihB[4], whhB[4], wlin[4];
  #pragma unroll
  for (int k = 0; k < 4; ++k) {
    const int j = e ^ k;
    wihA[k] = w_ih[rA * 4 + j];
    whhA[k] = w_hh[rA * 4 + j];
    wihB[k] = w_ih[rB * 4 + j];
    whhB[k] = w_hh[rB * 4 + j];
    wlin[k] = w_lin[j];
  }
  const float biasA = b_ih[rA] + b_hh[rA];
  const float biasB = b_ih[rB] + b_hh[rB];
  const float blin  = b_lin[0];
  // Uniform activation trick: aB = sB * sigmoid(sB * accB) + oB
  //   half0 (g): tanh(x) = 2*sigmoid(2x) - 1 ; half1 (o): sigmoid(x)
  const float sB = half0 ? 2.0f : 1.0f;
  const float oB = half0 ? -1.0f : 0.0f;
  const float L2E = 1.4426950408889634f; // log2(e)

  float c = 0.0f, h0 = 0.0f, h1 = 0.0f, h2 = 0.0f, h3 = 0.0f;

  const float* xlane = x + (size_t)b * 4 + e;   // x[t][b][e], stride B_DIM*4 floats per t
  float* olane = out + b;                        // out[t][b], stride B_DIM per t

  // software-pipelined x prefetch, depth 8
  float xb[8];
  #pragma unroll
  for (int k = 0; k < 8; ++k) xb[k] = xlane[(size_t)k * (B_DIM * 4)];

  for (int t0 = 0; t0 < T_DIM; t0 += 8) {
    int tn = t0 + 8;
    if (tn >= T_DIM) tn = 0;  // harmless wrap: loads stay valid, values unused
    const float* xq = xlane + (size_t)tn * (B_DIM * 4);
    float xn[8];
    #pragma unroll
    for (int k = 0; k < 8; ++k) xn[k] = xq[(size_t)k * (B_DIM * 4)];

    #pragma unroll
    for (int k = 0; k < 8; ++k) {
      // broadcast x[b][0..3] within quad, order [e, e^1, e^2, e^3]
      const float xe  = xb[k];
      const float xv1 = qperm_xor1(xe);
      const float xv2 = qperm_xor2(xe);
      const float xv3 = qperm_xor2(xv1);

      float accA = fmaf(wihA[0], xe,  biasA);
      accA = fmaf(wihA[1], xv1, accA);
      accA = fmaf(wihA[2], xv2, accA);
      accA = fmaf(wihA[3], xv3, accA);
      accA = fmaf(whhA[0], h0, accA);
      accA = fmaf(whhA[1], h1, accA);
      accA = fmaf(whhA[2], h2, accA);
      accA = fmaf(whhA[3], h3, accA);

      float accB = fmaf(wihB[0], xe,  biasB);
      accB = fmaf(wihB[1], xv1, accB);
      accB = fmaf(wihB[2], xv2, accB);
      accB = fmaf(wihB[3], xv3, accB);
      accB = fmaf(whhB[0], h0, accB);
      accB = fmaf(whhB[1], h1, accB);
      accB = fmaf(whhB[2], h2, accB);
      accB = fmaf(whhB[3], h3, accB);

      // activations: aA = sigmoid(accA) (i or f); aB = tanh(g) or sigmoid(o)
      const float aA = __builtin_amdgcn_rcpf(1.0f + exp2f(-L2E * accA));
      const float yB = __builtin_amdgcn_rcpf(1.0f + exp2f(-L2E * (sB * accB)));
      const float aB = fmaf(yB, sB, oB);

      // exchange across halves: half0 sends i*g, half1 sends f
      const float p  = aA * aB;             // half0: i*g (used); half1: f*o (dead)
      const float Z  = half0 ? p : aA;
      const float W  = swz_xor4(Z);
      const float F  = half0 ? W : Z;       // forget gate f
      const float Pv = half0 ? Z : W;       // i*g
      c = fmaf(F, c, Pv);

      // tanh(c) = 2*sigmoid(2c) - 1
      const float yC = __builtin_amdgcn_rcpf(1.0f + exp2f(-2.0f * L2E * c));
      const float tc = fmaf(2.0f, yC, -1.0f);

      // o lives on half1 (aB); ship to half0
      const float Ox = swz_xor4(aB);
      const float ov = half0 ? Ox : aB;
      const float hn = ov * tc;

      // broadcast new h within quad for next step + output head
      h0 = hn;
      h1 = qperm_xor1(hn);
      h2 = qperm_xor2(hn);
      h3 = qperm_xor2(h1);

      float acc = fmaf(wlin[0], h0, blin);
      acc = fmaf(wlin[1], h1, acc);
      acc = fmaf(wlin[2], h2, acc);
      acc = fmaf(wlin[3], h3, acc);
      const float outv = __builtin_amdgcn_rcpf(1.0f + exp2f(-L2E * acc));
      if (l == 0) olane[(size_t)(t0 + k) * B_DIM] = outv;
    }

    #pragma unroll
    for (int k = 0; k < 8; ++k) xb[k] = xn[k];
  }
}

extern "C" void kernel_launch(void* const* d_in, const int* in_sizes, int n_in,
                              void* d_out, int out_size, void* d_ws, size_t ws_size,
                              hipStream_t stream) {
  const float* x     = (const float*)d_in[0];
  const float* w_ih  = (const float*)d_in[1];
  const float* w_hh  = (const float*)d_in[2];
  const float* b_ih  = (const float*)d_in[3];
  const float* b_hh  = (const float*)d_in[4];
  const float* w_lin = (const float*)d_in[5];
  const float* b_lin = (const float*)d_in[6];
  float* out = (float*)d_out;

  const int threads = B_DIM * 8;  // 8 lanes per batch element
  dim3 block(256);
  dim3 grid(threads / 256);
  hipLaunchKernelGGL(lstm_scan_kernel, grid, block, 0, stream,
                     x, w_ih, w_hh, b_ih, b_hh, w_lin, b_lin, out);
}

// Round 2
// 352.301 us; speedup vs baseline: 1.5146x; 1.5146x over previous
//
#include <hip/hip_runtime.h>

#define T_DIM 2048
#define B_DIM 8192

// DPP cross-lane helpers (pure VALU, no LDS pipe)
__device__ __forceinline__ float dpp_qxor1(float v) {  // lane gets value from lane^1 (quad)
  int i = __float_as_int(v);
  return __int_as_float(__builtin_amdgcn_update_dpp(i, i, 0xB1, 0xF, 0xF, false)); // [1,0,3,2]
}
__device__ __forceinline__ float dpp_qxor2(float v) {  // lane gets value from lane^2 (quad)
  int i = __float_as_int(v);
  return __int_as_float(__builtin_amdgcn_update_dpp(i, i, 0x4E, 0xF, 0xF, false)); // [2,3,0,1]
}
__device__ __forceinline__ float dpp_hmirror(float v) { // lane l gets value from lane l^7 (8-lane mirror)
  int i = __float_as_int(v);
  return __int_as_float(__builtin_amdgcn_update_dpp(i, i, 0x141, 0xF, 0xF, false)); // row_half_mirror
}

__global__ __launch_bounds__(256) void lstm_scan_kernel(
    const float* __restrict__ x,
    const float* __restrict__ w_ih, const float* __restrict__ w_hh,
    const float* __restrict__ b_ih, const float* __restrict__ b_hh,
    const float* __restrict__ w_lin, const float* __restrict__ b_lin,
    float* __restrict__ out)
{
  const int tid = blockIdx.x * blockDim.x + threadIdx.x;
  const int l = tid & 7;          // lane within 8-lane group (one group per batch elem)
  const int b = tid >> 3;         // batch element
  const int half1 = (l >> 2) & 1; // 0: rows {i,g}; 1: rows {f,o}
  // Element labeling: half1 lanes own reversed elements so that the DPP
  // half-mirror partner (lane l^7) owns the SAME hidden element.
  const int e = (l & 3) ^ (half1 ? 3 : 0);

  // Gate rows owned by this lane (PyTorch order: i,f,g,o blocks of H=4)
  const int rA = half1 * 4 + e;        // i (half0) or f (half1)
  const int rB = 8 + half1 * 4 + e;    // g (half0) or o (half1)

  const float L2E = 1.4426950408889634f; // log2(e)
  // Pre-scale weights so activations are rcp(1+exp2(acc)) with no multiply:
  //   sigmoid(x) = 1/(1+2^(-L2E*x));  tanh(x) = 2/(1+2^(-2*L2E*x)) - 1
  const float sclA = -L2E;                          // i / f rows
  const float sclB = half1 ? -L2E : -2.0f * L2E;    // o row | g row

  // Pre-permuted weights: broadcast order is [e, e^1, e^2, e^3]
  float wihA[4], whhA[4], wihB[4], whhB[4], wlin[4];
  #pragma unroll
  for (int k = 0; k < 4; ++k) {
    const int j = e ^ k;
    wihA[k] = sclA * w_ih[rA * 4 + j];
    whhA[k] = sclA * w_hh[rA * 4 + j];
    wihB[k] = sclB * w_ih[rB * 4 + j];
    whhB[k] = sclB * w_hh[rB * 4 + j];
    wlin[k] = -L2E * w_lin[j];
  }
  const float biasA = sclA * (b_ih[rA] + b_hh[rA]);
  const float biasB = sclB * (b_ih[rB] + b_hh[rB]);
  const float blin  = -L2E * b_lin[0];
  // aB = sB * y + oB:  half0 (g): tanh = 2*y - 1 ; half1 (o): sigmoid = y
  const float sB = half1 ? 1.0f : 2.0f;
  const float oB = half1 ? 0.0f : -1.0f;

  float c = 0.0f, h0 = 0.0f, h1 = 0.0f, h2 = 0.0f, h3 = 0.0f;

  const float* xlane = x + (size_t)b * 4 + e;   // x[t][b][e]
  float* olane = out + b;                        // out[t][b]

  // Prefetch + precompute the x-projection (bias + W_ih * x) for 8 steps:
  // depends only on x, so it's off the recurrence critical path.
  float xaA[8], xaB[8];
  #pragma unroll
  for (int k = 0; k < 8; ++k) {
    const float xe  = xlane[(size_t)k * (B_DIM * 4)];
    const float xv1 = dpp_qxor1(xe);
    const float xv2 = dpp_qxor2(xe);
    const float xv3 = dpp_qxor2(xv1);
    float a = fmaf(wihA[0], xe, biasA);
    a = fmaf(wihA[1], xv1, a);
    a = fmaf(wihA[2], xv2, a);
    a = fmaf(wihA[3], xv3, a);
    xaA[k] = a;
    float bb = fmaf(wihB[0], xe, biasB);
    bb = fmaf(wihB[1], xv1, bb);
    bb = fmaf(wihB[2], xv2, bb);
    bb = fmaf(wihB[3], xv3, bb);
    xaB[k] = bb;
  }

  for (int t0 = 0; t0 < T_DIM; t0 += 8) {
    int tn = t0 + 8;
    if (tn >= T_DIM) tn = 0;  // harmless wrap: loads stay valid, values unused
    const float* xq = xlane + (size_t)tn * (B_DIM * 4);
    float xnA[8], xnB[8];
    #pragma unroll
    for (int k = 0; k < 8; ++k) {
      const float xe  = xq[(size_t)k * (B_DIM * 4)];
      const float xv1 = dpp_qxor1(xe);
      const float xv2 = dpp_qxor2(xe);
      const float xv3 = dpp_qxor2(xv1);
      float a = fmaf(wihA[0], xe, biasA);
      a = fmaf(wihA[1], xv1, a);
      a = fmaf(wihA[2], xv2, a);
      a = fmaf(wihA[3], xv3, a);
      xnA[k] = a;
      float bb = fmaf(wihB[0], xe, biasB);
      bb = fmaf(wihB[1], xv1, bb);
      bb = fmaf(wihB[2], xv2, bb);
      bb = fmaf(wihB[3], xv3, bb);
      xnB[k] = bb;
    }

    float ovout[8];
    #pragma unroll
    for (int k = 0; k < 8; ++k) {
      // gate accumulators: balanced-tree h-part on top of precomputed x-part
      float uA = fmaf(whhA[0], h0, xaA[k]);
      uA = fmaf(whhA[1], h1, uA);
      const float vA = fmaf(whhA[3], h3, whhA[2] * h2);
      const float accA = uA + vA;
      float uB = fmaf(whhB[0], h0, xaB[k]);
      uB = fmaf(whhB[1], h1, uB);
      const float vB = fmaf(whhB[3], h3, whhB[2] * h2);
      const float accB = uB + vB;

      // activations (pre-scaled): aA = sigmoid(i|f); aB = tanh(g) | sigmoid(o)
      const float aA = __builtin_amdgcn_rcpf(1.0f + __builtin_amdgcn_exp2f(accA));
      const float yB = __builtin_amdgcn_rcpf(1.0f + __builtin_amdgcn_exp2f(accB));
      const float aB = fmaf(sB, yB, oB);

      // exchange across halves via DPP mirror: half0 sends i*tanh(g), half1 sends f
      const float Z  = half1 ? aA : aA * aB;
      const float W  = dpp_hmirror(Z);
      const float F  = half1 ? Z : W;       // forget gate
      const float P  = half1 ? W : Z;       // i * tanh(g)
      c = fmaf(F, c, P);

      // tanh(c) = 2/(1+2^(-2*L2E*c)) - 1
      const float zc = __builtin_amdgcn_exp2f(-2.0f * L2E * c);
      const float tc = fmaf(2.0f, __builtin_amdgcn_rcpf(1.0f + zc), -1.0f);

      // o lives on half1; ship to half0 via mirror
      const float Ox = dpp_hmirror(aB);
      const float ov = half1 ? aB : Ox;
      const float hn = ov * tc;

      // broadcast new h within quad (order [e, e^1, e^2, e^3])
      h0 = hn;
      h1 = dpp_qxor1(hn);
      h2 = dpp_qxor2(hn);
      h3 = dpp_qxor2(h1);

      // output head (off critical path)
      float acc = fmaf(wlin[0], h0, blin);
      acc = fmaf(wlin[1], h1, acc);
      acc = fmaf(wlin[2], h2, acc);
      acc = fmaf(wlin[3], h3, acc);
      ovout[k] = __builtin_amdgcn_rcpf(1.0f + __builtin_amdgcn_exp2f(acc));
    }

    // one exec-masked store block per 8 steps (instead of per-step exec churn)
    if (l == 0) {
      #pragma unroll
      for (int k = 0; k < 8; ++k) olane[(size_t)(t0 + k) * B_DIM] = ovout[k];
    }

    #pragma unroll
    for (int k = 0; k < 8; ++k) { xaA[k] = xnA[k]; xaB[k] = xnB[k]; }
  }
}

extern "C" void kernel_launch(void* const* d_in, const int* in_sizes, int n_in,
                              void* d_out, int out_size, void* d_ws, size_t ws_size,
                              hipStream_t stream) {
  const float* x     = (const float*)d_in[0];
  const float* w_ih  = (const float*)d_in[1];
  const float* w_hh  = (const float*)d_in[2];
  const float* b_ih  = (const float*)d_in[3];
  const float* b_hh  = (const float*)d_in[4];
  const float* w_lin = (const float*)d_in[5];
  const float* b_lin = (const float*)d_in[6];
  float* out = (float*)d_out;

  const int threads = B_DIM * 8;  // 8 lanes per batch element
  dim3 block(256);
  dim3 grid(threads / 256);
  hipLaunchKernelGGL(lstm_scan_kernel, grid, block, 0, stream,
                     x, w_ih, w_hh, b_ih, b_hh, w_lin, b_lin, out);
}

// Round 3
// 296.528 us; speedup vs baseline: 1.7994x; 1.1881x over previous
//
#include <hip/hip_runtime.h>

#define T_DIM 2048
#define B_DIM 8192

// DPP cross-lane helpers (pure VALU, no LDS pipe)
__device__ __forceinline__ float dpp_qxor1(float v) {  // lane^1 within quad
  int i = __float_as_int(v);
  return __int_as_float(__builtin_amdgcn_update_dpp(i, i, 0xB1, 0xF, 0xF, false)); // [1,0,3,2]
}
__device__ __forceinline__ float dpp_qxor2(float v) {  // lane^2 within quad
  int i = __float_as_int(v);
  return __int_as_float(__builtin_amdgcn_update_dpp(i, i, 0x4E, 0xF, 0xF, false)); // [2,3,0,1]
}
__device__ __forceinline__ float dpp_qxor3(float v) {  // lane^3 within quad
  int i = __float_as_int(v);
  return __int_as_float(__builtin_amdgcn_update_dpp(i, i, 0x1B, 0xF, 0xF, false)); // [3,2,1,0]
}
__device__ __forceinline__ float dpp_hmirror(float v) { // lane l <- lane l^7
  int i = __float_as_int(v);
  return __int_as_float(__builtin_amdgcn_update_dpp(i, i, 0x141, 0xF, 0xF, false)); // row_half_mirror
}

__global__ __launch_bounds__(256) void lstm_scan_kernel(
    const float* __restrict__ x,
    const float* __restrict__ w_ih, const float* __restrict__ w_hh,
    const float* __restrict__ b_ih, const float* __restrict__ b_hh,
    const float* __restrict__ w_lin, const float* __restrict__ b_lin,
    float* __restrict__ out)
{
  const int tid = blockIdx.x * blockDim.x + threadIdx.x;
  const int l = tid & 7;          // lane within 8-lane group
  const int b = tid >> 3;         // batch element
  const int half1 = (l >> 2) & 1; // 0: rows {i,g}; 1: rows {f,o}
  // half1 lanes own reversed elements so the DPP half-mirror partner (l^7)
  // owns the SAME hidden element.
  const int e = (l & 3) ^ (half1 ? 3 : 0);

  const int rA = half1 * 4 + e;        // i | f row
  const int rB = 8 + half1 * 4 + e;    // g | o row

  const float L2E = 1.4426950408889634f;
  // Pre-scale so activations are rcp(1+exp2(acc)):
  //   sigmoid(x) = 1/(1+2^(-L2E x));  tanh(x) = 2/(1+2^(-2 L2E x)) - 1
  const float sclA = -L2E;
  const float sclB = half1 ? -L2E : -2.0f * L2E;

  float wihA[4], whhA[4], wihB[4], whhB[4], wlin[4];
  #pragma unroll
  for (int k = 0; k < 4; ++k) {
    const int j = e ^ k;
    wihA[k] = sclA * w_ih[rA * 4 + j];
    whhA[k] = sclA * w_hh[rA * 4 + j];
    wihB[k] = sclB * w_ih[rB * 4 + j];
    whhB[k] = sclB * w_hh[rB * 4 + j];
    wlin[k] = -L2E * w_lin[j];
  }
  const float biasA = sclA * (b_ih[rA] + b_hh[rA]);
  const float biasB = sclB * (b_ih[rB] + b_hh[rB]);
  const float blin  = -L2E * b_lin[0];
  const float sB = half1 ? 1.0f : 2.0f;   // aB = sB*y + oB (tanh | sigmoid)
  const float oB = half1 ? 0.0f : -1.0f;
  const float cm2 = -2.0f * L2E;

  float c = 0.0f, h0 = 0.0f, h1 = 0.0f, h2 = 0.0f, h3 = 0.0f;

  const float* xlane = x + (size_t)b * 4 + e;   // x[t][b][e]
  float* olane = out + b;                        // out[t][b]

  float r0[8], r1[8];                 // raw x, double-buffered (2-iter pipeline)
  float xaA0[8], xaB0[8], xaA1[8], xaB1[8];  // projected gate x-parts

  auto load8 = [&](float (&dst)[8], int t) {
    const float* p = xlane + (size_t)t * (B_DIM * 4);
    #pragma unroll
    for (int k = 0; k < 8; ++k) dst[k] = p[(size_t)k * (B_DIM * 4)];
  };

  auto proj1 = [&](float xe, float& oA, float& oBv) {
    const float xv1 = dpp_qxor1(xe);
    const float xv2 = dpp_qxor2(xe);
    const float xv3 = dpp_qxor3(xe);
    float a = fmaf(wihA[0], xe, biasA);
    a = fmaf(wihA[1], xv1, a);
    a = fmaf(wihA[2], xv2, a);
    a = fmaf(wihA[3], xv3, a);
    oA = a;
    float bb = fmaf(wihB[0], xe, biasB);
    bb = fmaf(wihB[1], xv1, bb);
    bb = fmaf(wihB[2], xv2, bb);
    bb = fmaf(wihB[3], xv3, bb);
    oBv = bb;
  };

  // 8 recurrence steps consuming (xaA,xaB); projects raw -> (xnA,xnB) as
  // per-step independent filler for the stall shadow of the serial chain.
  auto step8 = [&](int t0, float (&xaA)[8], float (&xaB)[8],
                   float (&raw)[8], float (&xnA)[8], float (&xnB)[8]) {
    float ovout[8];
    #pragma unroll
    for (int k = 0; k < 8; ++k) {
      // gates: balanced tree on precomputed x-part (h0 consumed first: it's
      // ready before h1..h3 DPP broadcasts land)
      float uA = fmaf(whhA[0], h0, xaA[k]);
      uA = fmaf(whhA[1], h1, uA);
      const float vA = fmaf(whhA[3], h3, whhA[2] * h2);
      const float accA = uA + vA;
      float uB = fmaf(whhB[0], h0, xaB[k]);
      uB = fmaf(whhB[1], h1, uB);
      const float vB = fmaf(whhB[3], h3, whhB[2] * h2);
      const float accB = uB + vB;

      // activations: aA = sigmoid(i|f); aB = tanh(g) | sigmoid(o)
      const float aA = __builtin_amdgcn_rcpf(1.0f + __builtin_amdgcn_exp2f(accA));
      const float yB = __builtin_amdgcn_rcpf(1.0f + __builtin_amdgcn_exp2f(accB));
      const float aB = fmaf(sB, yB, oB);

      // exchange across halves: half0 sends i*tanh(g), half1 sends f
      const float Z = half1 ? aA : aA * aB;
      const float W = dpp_hmirror(Z);
      const float F = half1 ? Z : W;
      const float P = half1 ? W : Z;
      c = fmaf(F, c, P);

      // tanh(c) = 2/(1+2^(cm2*c)) - 1
      const float zc = __builtin_amdgcn_exp2f(cm2 * c);
      const float rc = __builtin_amdgcn_rcpf(1.0f + zc);
      const float Ox = dpp_hmirror(aB);       // ship o to half0 (parallel w/ tc)
      const float ov = half1 ? aB : Ox;
      const float tc = fmaf(2.0f, rc, -1.0f);
      const float hn = ov * tc;

      // broadcast new h within quad — all three DPPs independent
      h0 = hn;
      h1 = dpp_qxor1(hn);
      h2 = dpp_qxor2(hn);
      h3 = dpp_qxor3(hn);

      // output head (off critical path)
      float acc = fmaf(wlin[0], h0, blin);
      acc = fmaf(wlin[1], h1, acc);
      acc = fmaf(wlin[2], h2, acc);
      acc = fmaf(wlin[3], h3, acc);
      ovout[k] = __builtin_amdgcn_rcpf(1.0f + __builtin_amdgcn_exp2f(acc));

      // independent filler: next-phase x-projection
      proj1(raw[k], xnA[k], xnB[k]);
    }
    if (l == 0) {
      #pragma unroll
      for (int k = 0; k < 8; ++k) olane[(size_t)(t0 + k) * B_DIM] = ovout[k];
    }
  };

  // Prologue: fill 2-iteration pipeline
  load8(r0, 0);
  load8(r1, 8);
  #pragma unroll
  for (int k = 0; k < 8; ++k) proj1(r0[k], xaA0[k], xaB0[k]);

  for (int t0 = 0; t0 < T_DIM; t0 += 16) {
    load8(r0, (t0 + 16) & (T_DIM - 1));            // issue early (wrap: unused)
    step8(t0,     xaA0, xaB0, r1, xaA1, xaB1);     // consume xa0, proj r1->xa1
    load8(r1, (t0 + 24) & (T_DIM - 1));
    step8(t0 + 8, xaA1, xaB1, r0, xaA0, xaB0);     // consume xa1, proj r0->xa0
  }
}

extern "C" void kernel_launch(void* const* d_in, const int* in_sizes, int n_in,
                              void* d_out, int out_size, void* d_ws, size_t ws_size,
                              hipStream_t stream) {
  const float* x     = (const float*)d_in[0];
  const float* w_ih  = (const float*)d_in[1];
  const float* w_hh  = (const float*)d_in[2];
  const float* b_ih  = (const float*)d_in[3];
  const float* b_hh  = (const float*)d_in[4];
  const float* w_lin = (const float*)d_in[5];
  const float* b_lin = (const float*)d_in[6];
  float* out = (float*)d_out;

  const int threads = B_DIM * 8;  // 8 lanes per batch element
  dim3 block(256);
  dim3 grid(threads / 256);
  hipLaunchKernelGGL(lstm_scan_kernel, grid, block, 0, stream,
                     x, w_ih, w_hh, b_ih, b_hh, w_lin, b_lin, out);
}

// Round 4
// 283.232 us; speedup vs baseline: 1.8839x; 1.0469x over previous
//
#include <hip/hip_runtime.h>

#define T_DIM 2048
#define B_DIM 8192

// DPP cross-lane helpers (pure VALU, no LDS pipe)
__device__ __forceinline__ float dpp_qxor1(float v) {  // lane^1 within quad
  int i = __float_as_int(v);
  return __int_as_float(__builtin_amdgcn_update_dpp(i, i, 0xB1, 0xF, 0xF, false)); // [1,0,3,2]
}
__device__ __forceinline__ float dpp_qxor2(float v) {  // lane^2 within quad
  int i = __float_as_int(v);
  return __int_as_float(__builtin_amdgcn_update_dpp(i, i, 0x4E, 0xF, 0xF, false)); // [2,3,0,1]
}
__device__ __forceinline__ float dpp_qxor3(float v) {  // lane^3 within quad
  int i = __float_as_int(v);
  return __int_as_float(__builtin_amdgcn_update_dpp(i, i, 0x1B, 0xF, 0xF, false)); // [3,2,1,0]
}
__device__ __forceinline__ float dpp_hmirror(float v) { // lane l <- lane l^7
  int i = __float_as_int(v);
  return __int_as_float(__builtin_amdgcn_update_dpp(i, i, 0x141, 0xF, 0xF, false)); // row_half_mirror
}

__global__ __launch_bounds__(256) void lstm_scan_kernel(
    const float* __restrict__ x,
    const float* __restrict__ w_ih, const float* __restrict__ w_hh,
    const float* __restrict__ b_ih, const float* __restrict__ b_hh,
    const float* __restrict__ w_lin, const float* __restrict__ b_lin,
    float* __restrict__ out)
{
  const int tid = blockIdx.x * blockDim.x + threadIdx.x;
  const int l = tid & 7;          // lane within 8-lane group
  const int b = tid >> 3;         // batch element
  const int half1 = (l >> 2) & 1; // 0: rows {i,g}; 1: rows {f,o}
  // half1 lanes own reversed elements so the DPP half-mirror partner (l^7)
  // owns the SAME hidden element.
  const int e = (l & 3) ^ (half1 ? 3 : 0);

  const int rA = half1 * 4 + e;        // i | f row
  const int rB = 8 + half1 * 4 + e;    // g | o row

  const float L2E = 1.4426950408889634f;
  const float cm2 = -2.0f * L2E;       // c is tracked pre-scaled: ct = cm2 * c
  // Pre-scale so activations are rcp(1+exp2(acc)):
  const float sclA = -L2E;                          // i | f rows (sigmoid)
  const float sclB = half1 ? -L2E : -2.0f * L2E;    // o row (sigmoid) | g row (tanh)

  float wihA[4], whhA[4], wihB[4], whhB[4];
  #pragma unroll
  for (int k = 0; k < 4; ++k) {
    const int j = e ^ k;
    wihA[k] = sclA * w_ih[rA * 4 + j];
    whhA[k] = sclA * w_hh[rA * 4 + j];
    wihB[k] = sclB * w_ih[rB * 4 + j];
    whhB[k] = sclB * w_hh[rB * 4 + j];
  }
  const float biasA = sclA * (b_ih[rA] + b_hh[rA]);
  const float biasB = sclB * (b_ih[rB] + b_hh[rB]);
  // aB:  half1: sigma(o) = y ;  half0: cm2*tanh(g) = (2*cm2)*y + (-cm2)
  //   (folding the cm2 scale of the c->tanh path into half0's g constants)
  const float sB = half1 ? 1.0f : 2.0f * cm2;
  const float oB = half1 ? 0.0f : -cm2;
  // head: out = sigmoid(w_lin . h + b_lin), pre-scaled for exp2 form
  const float wlo  = -L2E * w_lin[e];
  const float blin = -L2E * b_lin[0];

  float ct = 0.0f;                      // cm2 * c
  float h0 = 0.0f, h1 = 0.0f, h2 = 0.0f, h3 = 0.0f;
  float accK = 0.0f;                    // lane l keeps head pre-act of step t0+l

  const int XS = B_DIM * 4;             // x element stride per timestep
  const int xoff = b * 4 + e;           // 32-bit element offsets (max 64M -> fits)
  const int ooff = b + l * B_DIM;       // lane l stores step t0+l

  float r0[8], r1[8];                   // raw x, double-buffered
  float xaA0[8], xaB0[8], xaA1[8], xaB1[8];

  auto load8 = [&](float (&dst)[8], int tt) {
    const int base = xoff + tt * XS;
    #pragma unroll
    for (int k = 0; k < 8; ++k) dst[k] = x[base + k * XS];
  };

  auto proj1 = [&](float xe, float& oA, float& oBv) {
    const float xv1 = dpp_qxor1(xe);
    const float xv2 = dpp_qxor2(xe);
    const float xv3 = dpp_qxor3(xe);
    float a = fmaf(wihA[0], xe, biasA);
    a = fmaf(wihA[1], xv1, a);
    a = fmaf(wihA[2], xv2, a);
    a = fmaf(wihA[3], xv3, a);
    oA = a;
    float bb = fmaf(wihB[0], xe, biasB);
    bb = fmaf(wihB[1], xv1, bb);
    bb = fmaf(wihB[2], xv2, bb);
    bb = fmaf(wihB[3], xv3, bb);
    oBv = bb;
  };

  auto step8 = [&](int t0, float (&xaA)[8], float (&xaB)[8],
                   float (&raw)[8], float (&xnA)[8], float (&xnB)[8]) {
    #pragma unroll
    for (int k = 0; k < 8; ++k) {
      // gates: balanced tree on precomputed x-part
      float uA = fmaf(whhA[0], h0, xaA[k]);
      uA = fmaf(whhA[1], h1, uA);
      const float vA = fmaf(whhA[3], h3, whhA[2] * h2);
      const float accA = uA + vA;
      float uB = fmaf(whhB[0], h0, xaB[k]);
      uB = fmaf(whhB[1], h1, uB);
      const float vB = fmaf(whhB[3], h3, whhB[2] * h2);
      const float accB = uB + vB;

      // aA = sigmoid(i|f); aB = cm2*tanh(g) | sigmoid(o)
      const float aA = __builtin_amdgcn_rcpf(1.0f + __builtin_amdgcn_exp2f(accA));
      const float yB = __builtin_amdgcn_rcpf(1.0f + __builtin_amdgcn_exp2f(accB));
      const float aB = fmaf(sB, yB, oB);

      // exchange across halves: half0 sends cm2*(i*tanh g), half1 sends f
      const float Z = half1 ? aA : aA * aB;
      const float W = dpp_hmirror(Z);
      const float F = half1 ? Z : W;
      const float P = half1 ? W : Z;
      ct = fmaf(F, ct, P);            // ct stays cm2-scaled

      // tanh(c) = 2/(1+2^ct) - 1  (no mul: ct already scaled)
      const float zc = __builtin_amdgcn_exp2f(ct);
      const float rc = __builtin_amdgcn_rcpf(1.0f + zc);
      const float Ox = dpp_hmirror(aB);     // ship o to half0 (parallel w/ tc)
      const float ov = half1 ? aB : Ox;
      const float tc = fmaf(2.0f, rc, -1.0f);
      const float hn = ov * tc;

      // broadcast new h within quad
      h0 = hn;
      h1 = dpp_qxor1(hn);
      h2 = dpp_qxor2(hn);
      h3 = dpp_qxor3(hn);

      // head pre-activation via quad butterfly; lane k keeps step k's value
      float m = wlo * hn;
      m += dpp_qxor1(m);
      m += dpp_qxor2(m);
      accK = (l == k) ? m : accK;

      // independent filler: next-phase x-projection
      proj1(raw[k], xnA[k], xnB[k]);
    }
    // one sigmoid + one store per lane per 8 steps (lane l -> step t0+l)
    const float z = __builtin_amdgcn_exp2f(accK + blin);
    out[ooff + t0 * B_DIM] = __builtin_amdgcn_rcpf(1.0f + z);
  };

  // Prologue: fill 2-iteration pipeline
  load8(r0, 0);
  load8(r1, 8);
  #pragma unroll
  for (int k = 0; k < 8; ++k) proj1(r0[k], xaA0[k], xaB0[k]);

  for (int t0 = 0; t0 < T_DIM; t0 += 16) {
    load8(r0, (t0 + 16) & (T_DIM - 1));            // issue early (wrap: unused)
    step8(t0,     xaA0, xaB0, r1, xaA1, xaB1);
    load8(r1, (t0 + 24) & (T_DIM - 1));
    step8(t0 + 8, xaA1, xaB1, r0, xaA0, xaB0);
  }
}

extern "C" void kernel_launch(void* const* d_in, const int* in_sizes, int n_in,
                              void* d_out, int out_size, void* d_ws, size_t ws_size,
                              hipStream_t stream) {
  const float* x     = (const float*)d_in[0];
  const float* w_ih  = (const float*)d_in[1];
  const float* w_hh  = (const float*)d_in[2];
  const float* b_ih  = (const float*)d_in[3];
  const float* b_hh  = (const float*)d_in[4];
  const float* w_lin = (const float*)d_in[5];
  const float* b_lin = (const float*)d_in[6];
  float* out = (float*)d_out;

  const int threads = B_DIM * 8;  // 8 lanes per batch element
  dim3 block(256);
  dim3 grid(threads / 256);
  hipLaunchKernelGGL(lstm_scan_kernel, grid, block, 0, stream,
                     x, w_ih, w_hh, b_ih, b_hh, w_lin, b_lin, out);
}

// Round 6
// 248.940 us; speedup vs baseline: 2.1434x; 1.1378x over previous
//
#include <hip/hip_runtime.h>

#define T_DIM 2048
#define B_DIM 8192
#define PH    256   // phases
#define SPH   8     // steps per phase

// DPP cross-lane helpers (pure VALU)
__device__ __forceinline__ float dpp_qxor1(float v) {
  int i = __float_as_int(v);
  return __int_as_float(__builtin_amdgcn_update_dpp(i, i, 0xB1, 0xF, 0xF, false)); // [1,0,3,2]
}
__device__ __forceinline__ float dpp_qxor2(float v) {
  int i = __float_as_int(v);
  return __int_as_float(__builtin_amdgcn_update_dpp(i, i, 0x4E, 0xF, 0xF, false)); // [2,3,0,1]
}
__device__ __forceinline__ float dpp_qxor3(float v) {
  int i = __float_as_int(v);
  return __int_as_float(__builtin_amdgcn_update_dpp(i, i, 0x1B, 0xF, 0xF, false)); // [3,2,1,0]
}
__device__ __forceinline__ float dpp_hmirror(float v) { // lane l <- lane l^7
  int i = __float_as_int(v);
  return __int_as_float(__builtin_amdgcn_update_dpp(i, i, 0x141, 0xF, 0xF, false));
}

__global__ __launch_bounds__(512) void lstm_pc_kernel(
    const float* __restrict__ x,
    const float* __restrict__ w_ih, const float* __restrict__ w_hh,
    const float* __restrict__ b_ih, const float* __restrict__ b_hh,
    const float* __restrict__ w_lin, const float* __restrict__ b_lin,
    float* __restrict__ out)
{
  // [dbuf][pair][lane][...] ; padded inner dims (18, 9) for bank spread
  __shared__ float xaBuf[2][4][64][18];  // xaA at [2k], xaB at [2k+1]
  __shared__ float hnBuf[2][4][64][9];   // hn per (lane, step)

  const int tid  = threadIdx.x;
  const int wid  = tid >> 6;
  const int lane = tid & 63;
  const int pair = wid & 3;

  const float L2E = 1.4426950408889634f;
  const float cm2 = -2.0f * L2E;

  const int l = lane & 7;
  const int half1 = (l >> 2) & 1;            // 0: rows {i,g}; 1: rows {f,o}
  const int e = (l & 3) ^ (half1 ? 3 : 0);   // mirror partner owns same element
  const int grp = lane >> 3;
  const int rA = half1 * 4 + e;              // i | f row
  const int rB = 8 + half1 * 4 + e;          // g | o row
  const float sclA = -L2E;
  const float sclB = half1 ? -L2E : -2.0f * L2E;

  if (wid < 4) {
    // ---------------- recurrence waves (wid 0..3) ----------------
    __builtin_amdgcn_s_setprio(1);
    float whhA[4], whhB[4];
    #pragma unroll
    for (int k = 0; k < 4; ++k) {
      const int j = e ^ k;
      whhA[k] = sclA * w_hh[rA * 4 + j];
      whhB[k] = sclB * w_hh[rB * 4 + j];
    }
    const float sB = half1 ? 1.0f : 2.0f * cm2;  // aB = sB*y + oB
    const float oB = half1 ? 0.0f : -cm2;
    float ct = 0.0f, h0 = 0.0f, h1 = 0.0f, h2 = 0.0f, h3 = 0.0f;

    __syncthreads();  // wait for helper to fill xaBuf[0]

    for (int p = 0; p < PH; ++p) {
      const int d = p & 1;
      float xaA[SPH], xaB[SPH];
      #pragma unroll
      for (int k = 0; k < SPH; ++k) {
        xaA[k] = xaBuf[d][pair][lane][2 * k];
        xaB[k] = xaBuf[d][pair][lane][2 * k + 1];
      }
      #pragma unroll
      for (int k = 0; k < SPH; ++k) {
        float uA = fmaf(whhA[0], h0, xaA[k]);
        uA = fmaf(whhA[1], h1, uA);
        uA = fmaf(whhA[2], h2, uA);
        uA = fmaf(whhA[3], h3, uA);
        float uB = fmaf(whhB[0], h0, xaB[k]);
        uB = fmaf(whhB[1], h1, uB);
        uB = fmaf(whhB[2], h2, uB);
        uB = fmaf(whhB[3], h3, uB);
        const float aA = __builtin_amdgcn_rcpf(1.0f + __builtin_amdgcn_exp2f(uA));
        const float yB = __builtin_amdgcn_rcpf(1.0f + __builtin_amdgcn_exp2f(uB));
        const float aB = fmaf(sB, yB, oB);
        // exchange: half0 sends cm2*(i*tanh g), half1 sends f
        const float Z = half1 ? aA : aA * aB;
        const float W = dpp_hmirror(Z);
        const float F = half1 ? Z : W;
        const float P = half1 ? W : Z;
        ct = fmaf(F, ct, P);                       // ct is cm2-scaled c
        const float zc = __builtin_amdgcn_exp2f(ct);
        const float rc = __builtin_amdgcn_rcpf(1.0f + zc);
        const float Ox = dpp_hmirror(aB);          // ship o to half0
        const float ov = half1 ? aB : Ox;
        const float tc = fmaf(2.0f, rc, -1.0f);    // tanh(c)
        const float hn = ov * tc;
        h0 = hn;
        h1 = dpp_qxor1(hn);
        h2 = dpp_qxor2(hn);
        h3 = dpp_qxor3(hn);
        hnBuf[d][pair][lane][k] = hn;
      }
      __syncthreads();
    }
  } else {
    // ---------------- helper waves (wid 4..7) ----------------
    const int b = blockIdx.x * 32 + pair * 8 + grp;
    float wihA[4], wihB[4];
    #pragma unroll
    for (int k = 0; k < 4; ++k) {
      const int j = e ^ k;
      wihA[k] = sclA * w_ih[rA * 4 + j];
      wihB[k] = sclB * w_ih[rB * 4 + j];
    }
    const float biasA = sclA * (b_ih[rA] + b_hh[rA]);
    const float biasB = sclB * (b_ih[rB] + b_hh[rB]);
    // head assignment: lane -> (batch-group og, step oj)
    const int og = lane & 7, oj = lane >> 3;
    const int ob = blockIdx.x * 32 + pair * 8 + og;
    float wl[4];
    #pragma unroll
    for (int j = 0; j < 4; ++j) wl[j] = -L2E * w_lin[j];
    const float blin = -L2E * b_lin[0];

    const int XS = B_DIM * 4;
    const int xoff = b * 4 + e;

    float xc[SPH], xn[SPH];

    auto load8 = [&](float (&dst)[SPH], int ph) {
      const int base = xoff + ((ph & (PH - 1)) * SPH) * XS;  // wrap: harmless
      #pragma unroll
      for (int k = 0; k < SPH; ++k) dst[k] = x[base + k * XS];
    };
    auto projWrite = [&](const float (&xr)[SPH], int dd) {
      #pragma unroll
      for (int k = 0; k < SPH; ++k) {
        const float xe = xr[k];
        const float x1 = dpp_qxor1(xe);
        const float x2 = dpp_qxor2(xe);
        const float x3 = dpp_qxor3(xe);
        float a = fmaf(wihA[0], xe, biasA);
        a = fmaf(wihA[1], x1, a);
        a = fmaf(wihA[2], x2, a);
        a = fmaf(wihA[3], x3, a);
        float bb = fmaf(wihB[0], xe, biasB);
        bb = fmaf(wihB[1], x1, bb);
        bb = fmaf(wihB[2], x2, bb);
        bb = fmaf(wihB[3], x3, bb);
        xaBuf[dd][pair][lane][2 * k]     = a;
        xaBuf[dd][pair][lane][2 * k + 1] = bb;
      }
    };
    auto headStore = [&](int p, int dh) {
      const float v0 = hnBuf[dh][pair][og * 8 + 0][oj];
      const float v1 = hnBuf[dh][pair][og * 8 + 1][oj];
      const float v2 = hnBuf[dh][pair][og * 8 + 2][oj];
      const float v3 = hnBuf[dh][pair][og * 8 + 3][oj];
      float m = fmaf(wl[0], v0, blin);
      m = fmaf(wl[1], v1, m);
      m = fmaf(wl[2], v2, m);
      m = fmaf(wl[3], v3, m);
      const float o = __builtin_amdgcn_rcpf(1.0f + __builtin_amdgcn_exp2f(m));
      out[(size_t)(p * SPH + oj) * B_DIM + ob] = o;
    };

    // prologue: xa for phase 0 -> buf0; start loading x for phase 1
    load8(xc, 0);
    projWrite(xc, 0);
    load8(xn, 1);
    __syncthreads();

    for (int pp = 0; pp < PH; pp += 2) {
      // phase pp: write xa(pp+1)->buf1; load x(pp+2); head(pp-1) from buf1
      projWrite(xn, 1);
      load8(xc, pp + 2);
      if (pp > 0) headStore(pp - 1, 1);
      __syncthreads();
      // phase pp+1: write xa(pp+2)->buf0; load x(pp+3); head(pp) from buf0
      projWrite(xc, 0);
      load8(xn, pp + 3);
      headStore(pp, 0);
      __syncthreads();
    }
    headStore(PH - 1, 1);  // last phase's head
  }
}

extern "C" void kernel_launch(void* const* d_in, const int* in_sizes, int n_in,
                              void* d_out, int out_size, void* d_ws, size_t ws_size,
                              hipStream_t stream) {
  const float* x     = (const float*)d_in[0];
  const float* w_ih  = (const float*)d_in[1];
  const float* w_hh  = (const float*)d_in[2];
  const float* b_ih  = (const float*)d_in[3];
  const float* b_hh  = (const float*)d_in[4];
  const float* w_lin = (const float*)d_in[5];
  const float* b_lin = (const float*)d_in[6];
  float* out = (float*)d_out;

  // 256 blocks x 512 threads: 4 recurrence waves + 4 helper waves per block,
  // 32 batch elems per block -> 8192/32 = 256 blocks.
  // 256 blocks * 8 waves = 2048 waves = 2 waves/SIMD (recurrence + helper).
  dim3 block(512);
  dim3 grid(B_DIM / 32);
  hipLaunchKernelGGL(lstm_pc_kernel, grid, block, 0, stream,
                     x, w_ih, w_hh, b_ih, b_hh, w_lin, b_lin, out);
}

// Round 7
// 237.605 us; speedup vs baseline: 2.2457x; 1.0477x over previous
//
#include <hip/hip_runtime.h>

#define T_DIM 2048
#define B_DIM 8192
#define PH    256   // phases
#define SPH   8     // steps per phase

// DPP cross-lane helpers (pure VALU)
__device__ __forceinline__ float dpp_qxor1(float v) {
  int i = __float_as_int(v);
  return __int_as_float(__builtin_amdgcn_update_dpp(i, i, 0xB1, 0xF, 0xF, false)); // [1,0,3,2]
}
__device__ __forceinline__ float dpp_qxor2(float v) {
  int i = __float_as_int(v);
  return __int_as_float(__builtin_amdgcn_update_dpp(i, i, 0x4E, 0xF, 0xF, false)); // [2,3,0,1]
}
__device__ __forceinline__ float dpp_qxor3(float v) {
  int i = __float_as_int(v);
  return __int_as_float(__builtin_amdgcn_update_dpp(i, i, 0x1B, 0xF, 0xF, false)); // [3,2,1,0]
}
__device__ __forceinline__ float dpp_hmirror(float v) { // lane l <- lane l^7
  int i = __float_as_int(v);
  return __int_as_float(__builtin_amdgcn_update_dpp(i, i, 0x141, 0xF, 0xF, false));
}

__global__ __launch_bounds__(768) void lstm_pc3_kernel(
    const float* __restrict__ x,
    const float* __restrict__ w_ih, const float* __restrict__ w_hh,
    const float* __restrict__ b_ih, const float* __restrict__ b_hh,
    const float* __restrict__ w_lin, const float* __restrict__ b_lin,
    float* __restrict__ out)
{
  // Odd strides (17, 9) -> conflict-free LDS banking for row-per-lane access
  __shared__ float xaBuf[2][4][64][17];  // xaA at [2k], xaB at [2k+1]
  __shared__ float hnBuf[2][4][64][9];   // hn per (lane, step)

  const int tid  = threadIdx.x;
  const int wid  = tid >> 6;       // 0..11
  const int lane = tid & 63;
  const int pair = wid & 3;

  const float L2E = 1.4426950408889634f;
  const float cm2 = -2.0f * L2E;

  const int l = lane & 7;
  const int half1 = (l >> 2) & 1;            // 0: rows {i,g}; 1: rows {f,o}
  const int e = (l & 3) ^ (half1 ? 3 : 0);   // mirror partner owns same element
  const int grp = lane >> 3;
  const int rA = half1 * 4 + e;              // i | f row
  const int rB = 8 + half1 * 4 + e;          // g | o row
  const float sclA = -L2E;
  const float sclB = half1 ? -L2E : -2.0f * L2E;

  if (wid < 4) {
    // ---------------- recurrence waves (wid 0..3): 257 barriers ----------------
    __builtin_amdgcn_s_setprio(1);
    float whhA[4], whhB[4];
    #pragma unroll
    for (int k = 0; k < 4; ++k) {
      const int j = e ^ k;
      whhA[k] = sclA * w_hh[rA * 4 + j];
      whhB[k] = sclB * w_hh[rB * 4 + j];
    }
    const float sB = half1 ? 1.0f : 2.0f * cm2;  // aB = sB*y + oB
    const float oB = half1 ? 0.0f : -cm2;
    float ct = 0.0f, h0 = 0.0f, h1 = 0.0f, h2 = 0.0f, h3 = 0.0f;

    __syncthreads();  // wait for proj waves to fill xaBuf[0]

    for (int p = 0; p < PH; ++p) {
      const int d = p & 1;
      float xaA[SPH], xaB[SPH];
      #pragma unroll
      for (int k = 0; k < SPH; ++k) {
        xaA[k] = xaBuf[d][pair][lane][2 * k];
        xaB[k] = xaBuf[d][pair][lane][2 * k + 1];
      }
      #pragma unroll
      for (int k = 0; k < SPH; ++k) {
        float uA = fmaf(whhA[0], h0, xaA[k]);
        uA = fmaf(whhA[1], h1, uA);
        uA = fmaf(whhA[2], h2, uA);
        uA = fmaf(whhA[3], h3, uA);
        float uB = fmaf(whhB[0], h0, xaB[k]);
        uB = fmaf(whhB[1], h1, uB);
        uB = fmaf(whhB[2], h2, uB);
        uB = fmaf(whhB[3], h3, uB);
        const float aA = __builtin_amdgcn_rcpf(1.0f + __builtin_amdgcn_exp2f(uA));
        const float yB = __builtin_amdgcn_rcpf(1.0f + __builtin_amdgcn_exp2f(uB));
        const float aB = fmaf(sB, yB, oB);
        // exchange: half0 sends cm2*(i*tanh g), half1 sends f
        const float Z = half1 ? aA : aA * aB;
        const float W = dpp_hmirror(Z);
        const float F = half1 ? Z : W;
        const float P = half1 ? W : Z;
        ct = fmaf(F, ct, P);                       // ct is cm2-scaled c
        const float zc = __builtin_amdgcn_exp2f(ct);
        const float rc = __builtin_amdgcn_rcpf(1.0f + zc);
        const float Ox = dpp_hmirror(aB);          // ship o to half0
        const float ov = half1 ? aB : Ox;
        const float tc = fmaf(2.0f, rc, -1.0f);    // tanh(c)
        const float hn = ov * tc;
        h0 = hn;
        h1 = dpp_qxor1(hn);
        h2 = dpp_qxor2(hn);
        h3 = dpp_qxor3(hn);
        hnBuf[d][pair][lane][k] = hn;
      }
      __syncthreads();
    }
  } else if (wid < 8) {
    // ---------------- proj/load waves (wid 4..7): 257 barriers ----------------
    const int b = blockIdx.x * 32 + pair * 8 + grp;
    float wihA[4], wihB[4];
    #pragma unroll
    for (int k = 0; k < 4; ++k) {
      const int j = e ^ k;
      wihA[k] = sclA * w_ih[rA * 4 + j];
      wihB[k] = sclB * w_ih[rB * 4 + j];
    }
    const float biasA = sclA * (b_ih[rA] + b_hh[rA]);
    const float biasB = sclB * (b_ih[rB] + b_hh[rB]);

    const int XS = B_DIM * 4;
    const int xoff = b * 4 + e;

    float xc[SPH], xn[SPH];

    auto load8 = [&](float (&dst)[SPH], int ph) {
      const int base = xoff + ((ph & (PH - 1)) * SPH) * XS;  // wrap: harmless
      #pragma unroll
      for (int k = 0; k < SPH; ++k) dst[k] = x[base + k * XS];
    };
    auto projWrite = [&](const float (&xr)[SPH], int dd) {
      #pragma unroll
      for (int k = 0; k < SPH; ++k) {
        const float xe = xr[k];
        const float x1 = dpp_qxor1(xe);
        const float x2 = dpp_qxor2(xe);
        const float x3 = dpp_qxor3(xe);
        float a = fmaf(wihA[0], xe, biasA);
        a = fmaf(wihA[1], x1, a);
        a = fmaf(wihA[2], x2, a);
        a = fmaf(wihA[3], x3, a);
        float bb = fmaf(wihB[0], xe, biasB);
        bb = fmaf(wihB[1], x1, bb);
        bb = fmaf(wihB[2], x2, bb);
        bb = fmaf(wihB[3], x3, bb);
        xaBuf[dd][pair][lane][2 * k]     = a;
        xaBuf[dd][pair][lane][2 * k + 1] = bb;
      }
    };

    // prologue: xa for phase 0 -> buf0; start loading x for phase 1
    load8(xc, 0);
    projWrite(xc, 0);
    load8(xn, 1);
    __syncthreads();

    for (int pp = 0; pp < PH; pp += 2) {
      projWrite(xn, 1);           // xa(pp+1) -> buf1
      load8(xc, pp + 2);
      __syncthreads();
      projWrite(xc, 0);           // xa(pp+2) -> buf0
      load8(xn, pp + 3);
      __syncthreads();
    }
  } else {
    // ---------------- head/store waves (wid 8..11): 257 barriers ----------------
    const int og = lane & 7, oj = lane >> 3;
    const int ob = blockIdx.x * 32 + pair * 8 + og;
    float wl[4];
    #pragma unroll
    for (int j = 0; j < 4; ++j) wl[j] = -L2E * w_lin[j];
    const float blin = -L2E * b_lin[0];

    __syncthreads();  // initial barrier (matches other roles)

    for (int p = 0; p < PH; ++p) {
      __syncthreads();  // barrier ending phase p -> hnBuf[p&1] is complete
      const int dh = p & 1;
      const float v0 = hnBuf[dh][pair][og * 8 + 0][oj];
      const float v1 = hnBuf[dh][pair][og * 8 + 1][oj];
      const float v2 = hnBuf[dh][pair][og * 8 + 2][oj];
      const float v3 = hnBuf[dh][pair][og * 8 + 3][oj];
      float m = fmaf(wl[0], v0, blin);
      m = fmaf(wl[1], v1, m);
      m = fmaf(wl[2], v2, m);
      m = fmaf(wl[3], v3, m);
      const float o = __builtin_amdgcn_rcpf(1.0f + __builtin_amdgcn_exp2f(m));
      out[(size_t)(p * SPH + oj) * B_DIM + ob] = o;
    }
  }
}

extern "C" void kernel_launch(void* const* d_in, const int* in_sizes, int n_in,
                              void* d_out, int out_size, void* d_ws, size_t ws_size,
                              hipStream_t stream) {
  const float* x     = (const float*)d_in[0];
  const float* w_ih  = (const float*)d_in[1];
  const float* w_hh  = (const float*)d_in[2];
  const float* b_ih  = (const float*)d_in[3];
  const float* b_hh  = (const float*)d_in[4];
  const float* w_lin = (const float*)d_in[5];
  const float* b_lin = (const float*)d_in[6];
  float* out = (float*)d_out;

  // 256 blocks x 768 threads: 4 recurrence + 4 proj + 4 head waves per block,
  // 32 batch elems per block. 3072 waves total = 3 waves/SIMD, one of each
  // role per SIMD (round-robin wave placement).
  dim3 block(768);
  dim3 grid(B_DIM / 32);
  hipLaunchKernelGGL(lstm_pc3_kernel, grid, block, 0, stream,
                     x, w_ih, w_hh, b_ih, b_hh, w_lin, b_lin, out);
}